// Round 5
// baseline (143.850 us; speedup 1.0000x reference)
//
#include <hip/hip_runtime.h>
#include <hip/hip_bf16.h>

// Problem constants
#define B 64
#define S 512
#define D 768
#define K 8
#define R 277
#define NSPAN 10     // h, t, 8 bridge spans per batch
#define M_TOT 640    // pooled rows: [u: 0..63][v: 64..127][bi: 128..639]

// ---------------------------------------------------------------------------
// Pool phase 1 (streaming, branchless): one block per (b, s-chunk). Streams
// all RPC rows of its chunk unconditionally (RPC independent float4 loads,
// fully unrolled -> deep MLP), updating all 10 span accumulators with
// select+fmax. Blocks whose chunk intersects no span exit before loading.
// 192 threads; thread t owns float4 slot t of the 768-dim row.
// ---------------------------------------------------------------------------
template<int RPC>
__global__ void k_pool1(const float* __restrict__ emb,
                        const int* __restrict__ h_span,
                        const int* __restrict__ t_span,
                        const int* __restrict__ b_spans,
                        float* __restrict__ partial) {
    int b = blockIdx.x, c = blockIdx.y;
    int nch = S / RPC;
    int r0 = c * RPC;
    int t = threadIdx.x;

    int s0[NSPAN], s1[NSPAN];
    s0[0] = h_span[b*2]; s1[0] = h_span[b*2+1];
    s0[1] = t_span[b*2]; s1[1] = t_span[b*2+1];
    #pragma unroll
    for (int k = 0; k < K; ++k) {
        s0[2+k] = b_spans[(b*K+k)*2];
        s1[2+k] = b_spans[(b*K+k)*2 + 1];
    }

    bool any = false;
    #pragma unroll
    for (int j = 0; j < NSPAN; ++j)
        any |= (s1[j] >= r0) && (s0[j] < r0 + RPC);
    if (!any) return;                      // wave-uniform: untouched chunk

    float4 m[NSPAN];
    #pragma unroll
    for (int j = 0; j < NSPAN; ++j)
        m[j] = make_float4(-INFINITY, -INFINITY, -INFINITY, -INFINITY);

    const float4* e4 = (const float4*)(emb + (size_t)b * S * D) + (size_t)r0 * (D/4) + t;
    #pragma unroll
    for (int i = 0; i < RPC; ++i) {
        float4 v = e4[i * (D/4)];
        int s = r0 + i;
        #pragma unroll
        for (int j = 0; j < NSPAN; ++j) {
            bool in = (s >= s0[j]) && (s <= s1[j]);
            float vx = in ? v.x : -INFINITY;
            float vy = in ? v.y : -INFINITY;
            float vz = in ? v.z : -INFINITY;
            float vw = in ? v.w : -INFINITY;
            m[j].x = fmaxf(m[j].x, vx); m[j].y = fmaxf(m[j].y, vy);
            m[j].z = fmaxf(m[j].z, vz); m[j].w = fmaxf(m[j].w, vw);
        }
    }

    #pragma unroll
    for (int j = 0; j < NSPAN; ++j) {
        if (s1[j] >= r0 && s0[j] < r0 + RPC) {   // uniform: span intersects chunk
            *(float4*)(partial + (((size_t)(b*nch + c))*NSPAN + j) * D + t*4) = m[j];
        }
    }
}

// ---------------------------------------------------------------------------
// Pool phase 2: one block per (b, span j). Reduces only the chunks that
// intersect the span (recomputed from inputs — untouched partials never read).
// ---------------------------------------------------------------------------
__global__ void k_pool2(const float* __restrict__ partial,
                        const int* __restrict__ h_span,
                        const int* __restrict__ t_span,
                        const int* __restrict__ b_spans,
                        float* __restrict__ pooled, int rpc) {
    int task = blockIdx.x;             // 0..639
    int b = task / NSPAN, j = task % NSPAN;
    int s0, s1, row;
    if (j == 0)      { s0 = h_span[b*2]; s1 = h_span[b*2+1]; row = b; }
    else if (j == 1) { s0 = t_span[b*2]; s1 = t_span[b*2+1]; row = B + b; }
    else {
        int k = j - 2;
        s0 = b_spans[(b*K+k)*2]; s1 = b_spans[(b*K+k)*2 + 1];
        row = 2*B + b*K + k;
    }
    int nch = S / rpc;
    int c0 = s0 / rpc, c1 = s1 / rpc;
    int t = threadIdx.x;
    float4 m = make_float4(-INFINITY, -INFINITY, -INFINITY, -INFINITY);
    for (int c = c0; c <= c1; ++c) {
        float4 v = *(const float4*)(partial + (((size_t)(b*nch + c))*NSPAN + j) * D + t*4);
        m.x = fmaxf(m.x, v.x); m.y = fmaxf(m.y, v.y);
        m.z = fmaxf(m.z, v.z); m.w = fmaxf(m.w, v.w);
    }
    ((float4*)(pooled + (size_t)row * D))[t] = m;
}

// ---------------------------------------------------------------------------
// GEMM: p_part[ks][m][e] = sum_{d in ks-range} pooled[m][d] * W_m[e][d]
// 64x64 tiles, 4x4 register tiles, both operands staged transposed in LDS.
// grid = (12, 10, KSPLIT), block = 256.
// ---------------------------------------------------------------------------
template<int KSPLIT>
__global__ void k_gemm(const float* __restrict__ pooled,
                       const float* __restrict__ wu,
                       const float* __restrict__ wv,
                       const float* __restrict__ wi,
                       float* __restrict__ p_part) {
    __shared__ float At[16][68];
    __shared__ float Wt[16][68];
    int e0 = blockIdx.x * 64;
    int m0 = blockIdx.y * 64;
    const int klen = D / KSPLIT;
    int dbase = blockIdx.z * klen;
    const float* Wm = (m0 < B) ? wu : (m0 < 2*B) ? wv : wi;

    int tid = threadIdx.x;
    int tx = tid & 15, ty = tid >> 4;
    int lm = tid >> 2;
    int ld = (tid & 3) * 4;

    float acc[4][4] = {};
    const int kchunks = klen / 16;
    #pragma unroll 2
    for (int kc = 0; kc < kchunks; ++kc) {
        int d0 = dbase + kc * 16;
        float4 a4 = *(const float4*)(pooled + (size_t)(m0 + lm) * D + d0 + ld);
        float4 w4 = *(const float4*)(Wm     + (size_t)(e0 + lm) * D + d0 + ld);
        __syncthreads();
        At[ld+0][lm] = a4.x; At[ld+1][lm] = a4.y; At[ld+2][lm] = a4.z; At[ld+3][lm] = a4.w;
        Wt[ld+0][lm] = w4.x; Wt[ld+1][lm] = w4.y; Wt[ld+2][lm] = w4.z; Wt[ld+3][lm] = w4.w;
        __syncthreads();
        #pragma unroll
        for (int dd = 0; dd < 16; ++dd) {
            float4 av  = *(const float4*)&At[dd][ty << 2];
            float4 wvv = *(const float4*)&Wt[dd][tx << 2];
            float a_[4] = {av.x, av.y, av.z, av.w};
            float w_[4] = {wvv.x, wvv.y, wvv.z, wvv.w};
            #pragma unroll
            for (int i = 0; i < 4; ++i)
                #pragma unroll
                for (int jj = 0; jj < 4; ++jj)
                    acc[i][jj] += a_[i] * w_[jj];
        }
    }
    #pragma unroll
    for (int i = 0; i < 4; ++i) {
        float4 o = make_float4(acc[i][0], acc[i][1], acc[i][2], acc[i][3]);
        *(float4*)(p_part + ((size_t)blockIdx.z * M_TOT + m0 + ty*4 + i) * D + e0 + tx*4) = o;
    }
}

// ---------------------------------------------------------------------------
// Fused tail: att (bias+partial-reduce, dots, softmax, ctx) + pair + pred.
// One block per b, 512 threads (8 waves). GEMVs are wave-per-row with
// coalesced float4 weight reads + shfl-xor cross-lane reduce.
// ---------------------------------------------------------------------------
template<int KSPLIT>
__global__ __launch_bounds__(512)
void k_tail(const float* __restrict__ p_part,
            const float* __restrict__ wu_b,
            const float* __restrict__ wv_b,
            const float* __restrict__ wi_b,
            const float* __restrict__ ln1_w,
            const float* __restrict__ ln1_b,
            const float* __restrict__ pred_w,
            const float* __restrict__ pred_b,
            float* __restrict__ out) {
    __shared__ float U[D], V[D], BI[K][D];
    __shared__ float Sx[D], P[D];
    __shared__ float dots[K];
    int b = blockIdx.x, tid = threadIdx.x;

    // 1) reduce KSPLIT partials + bias into U, V, BI (coalesced float4)
    for (int task = tid; task < NSPAN * (D/4); task += 512) {
        int j = task / (D/4), sl = task % (D/4);
        size_t row = (j == 0) ? (size_t)b : (j == 1) ? (size_t)(B + b)
                   : (size_t)(2*B + b*K + (j - 2));
        const float* bias = (j == 0) ? wu_b : (j == 1) ? wv_b : wi_b;
        float4 acc = *(const float4*)(bias + sl*4);
        #pragma unroll
        for (int ks = 0; ks < KSPLIT; ++ks) {
            float4 p = *(const float4*)(p_part + ((size_t)ks * M_TOT + row) * D + sl*4);
            acc.x += p.x; acc.y += p.y; acc.z += p.z; acc.w += p.w;
        }
        float* dst = (j == 0) ? U : (j == 1) ? V : BI[j-2];
        *(float4*)(dst + sl*4) = acc;
    }
    __syncthreads();

    // 2) attention dots: wave w computes dot(U, BI[w]) — 8 waves = K
    int wave = tid >> 6, lane = tid & 63;
    {
        float part = 0.f;
        #pragma unroll
        for (int i = 0; i < D/64; ++i) {
            int d = i*64 + lane;
            part += U[d] * BI[wave][d];
        }
        #pragma unroll
        for (int off = 32; off > 0; off >>= 1) part += __shfl_xor(part, off);
        if (lane == 0) dots[wave] = part * 0.125f;   // 1/sqrt(D_K=64)
    }
    __syncthreads();

    // 3) softmax (redundant per-thread) + Sx = U + V + ctx
    float mx = -INFINITY;
    #pragma unroll
    for (int k = 0; k < K; ++k) mx = fmaxf(mx, dots[k]);
    float ex[K], sum = 0.f;
    #pragma unroll
    for (int k = 0; k < K; ++k) { ex[k] = expf(dots[k] - mx); sum += ex[k]; }
    float inv = 1.f / sum;
    for (int d = tid; d < D; d += 512) {
        float c = 0.f;
        #pragma unroll
        for (int k = 0; k < K; ++k) c += ex[k] * BI[k][d];
        Sx[d] = U[d] + V[d] + c * inv;
    }
    __syncthreads();

    // 4) pair GEMV: wave-per-row, coalesced W reads, relu into P
    for (int e = wave; e < D; e += 8) {
        const float4* wr = (const float4*)(ln1_w + (size_t)e * D);
        float a = 0.f;
        #pragma unroll
        for (int i = 0; i < 3; ++i) {
            float4 w4 = wr[i*64 + lane];
            float4 x4 = *(const float4*)&Sx[(i*64 + lane) * 4];
            a += w4.x*x4.x + w4.y*x4.y + w4.z*x4.z + w4.w*x4.w;
        }
        #pragma unroll
        for (int off = 32; off > 0; off >>= 1) a += __shfl_xor(a, off);
        if (lane == 0) P[e] = fmaxf(a + ln1_b[e], 0.f);
    }
    __syncthreads();

    // 5) pred GEMV: wave-per-row -> logits
    for (int r = wave; r < R; r += 8) {
        const float4* wr = (const float4*)(pred_w + (size_t)r * D);
        float a = 0.f;
        #pragma unroll
        for (int i = 0; i < 3; ++i) {
            float4 w4 = wr[i*64 + lane];
            float4 x4 = *(const float4*)&P[(i*64 + lane) * 4];
            a += w4.x*x4.x + w4.y*x4.y + w4.z*x4.z + w4.w*x4.w;
        }
        #pragma unroll
        for (int off = 32; off > 0; off >>= 1) a += __shfl_xor(a, off);
        if (lane == 0) out[(size_t)b * R + r] = a + pred_b[r];
    }
}

// ---------------------------------------------------------------------------
extern "C" void kernel_launch(void* const* d_in, const int* in_sizes, int n_in,
                              void* d_out, int out_size, void* d_ws, size_t ws_size,
                              hipStream_t stream) {
    const float* emb     = (const float*)d_in[0];
    const int*   h_span  = (const int*)  d_in[1];
    const int*   t_span  = (const int*)  d_in[2];
    const int*   b_spans = (const int*)  d_in[3];
    const float* wu_w    = (const float*)d_in[4];
    const float* wu_b    = (const float*)d_in[5];
    const float* wv_w    = (const float*)d_in[6];
    const float* wv_b    = (const float*)d_in[7];
    const float* wi_w    = (const float*)d_in[8];
    const float* wi_b    = (const float*)d_in[9];
    const float* ln1_w   = (const float*)d_in[10];
    const float* ln1_b   = (const float*)d_in[11];
    const float* pred_w  = (const float*)d_in[12];
    const float* pred_b  = (const float*)d_in[13];
    float* out = (float*)d_out;

    const int KSPLIT = 4;
    size_t avail = ws_size / sizeof(float);
    auto need = [&](int nch_) -> size_t {
        return (size_t)M_TOT*D + (size_t)KSPLIT*M_TOT*D + (size_t)B*nch_*NSPAN*D;
    };
    int nch = (need(32) <= avail) ? 32 : 16;

    float* ws      = (float*)d_ws;
    float* pooled  = ws;                                   // M_TOT*D
    float* p_part  = pooled + (size_t)M_TOT * D;           // KSPLIT*M_TOT*D
    float* partial = p_part + (size_t)KSPLIT * M_TOT * D;  // B*nch*NSPAN*D

    if (nch == 32)
        k_pool1<16><<<dim3(B, 32), 192, 0, stream>>>(emb, h_span, t_span, b_spans, partial);
    else
        k_pool1<32><<<dim3(B, 16), 192, 0, stream>>>(emb, h_span, t_span, b_spans, partial);
    k_pool2<<<M_TOT, 192, 0, stream>>>(partial, h_span, t_span, b_spans, pooled, S / nch);
    k_gemm<KSPLIT><<<dim3(D/64, M_TOT/64, KSPLIT), 256, 0, stream>>>(pooled, wu_w, wv_w, wi_w, p_part);
    k_tail<KSPLIT><<<B, 512, 0, stream>>>(p_part, wu_b, wv_b, wi_b,
                                          ln1_w, ln1_b, pred_w, pred_b, out);
}

// Round 6
// 82.167 us; speedup vs baseline: 1.7507x; 1.7507x over previous
//
#include <hip/hip_runtime.h>
#include <hip/hip_bf16.h>

// Problem constants
#define B 64
#define S 512
#define D 768
#define K 8
#define R 277
#define RPAD 320     // R padded to 5*64 for the pred GEMM
#define NSPAN 10     // h, t, 8 bridge spans per batch
#define M_TOT 640    // pooled rows: [u: 0..63][v: 64..127][bi: 128..639]

// ---------------------------------------------------------------------------
// Pool phase 1 (streaming, branchless): one block per (b, s-chunk).
// ---------------------------------------------------------------------------
template<int RPC>
__global__ void k_pool1(const float* __restrict__ emb,
                        const int* __restrict__ h_span,
                        const int* __restrict__ t_span,
                        const int* __restrict__ b_spans,
                        float* __restrict__ partial) {
    int b = blockIdx.x, c = blockIdx.y;
    int nch = S / RPC;
    int r0 = c * RPC;
    int t = threadIdx.x;

    int s0[NSPAN], s1[NSPAN];
    s0[0] = h_span[b*2]; s1[0] = h_span[b*2+1];
    s0[1] = t_span[b*2]; s1[1] = t_span[b*2+1];
    #pragma unroll
    for (int k = 0; k < K; ++k) {
        s0[2+k] = b_spans[(b*K+k)*2];
        s1[2+k] = b_spans[(b*K+k)*2 + 1];
    }

    bool any = false;
    #pragma unroll
    for (int j = 0; j < NSPAN; ++j)
        any |= (s1[j] >= r0) && (s0[j] < r0 + RPC);
    if (!any) return;

    float4 m[NSPAN];
    #pragma unroll
    for (int j = 0; j < NSPAN; ++j)
        m[j] = make_float4(-INFINITY, -INFINITY, -INFINITY, -INFINITY);

    const float4* e4 = (const float4*)(emb + (size_t)b * S * D) + (size_t)r0 * (D/4) + t;
    #pragma unroll
    for (int i = 0; i < RPC; ++i) {
        float4 v = e4[i * (D/4)];
        int s = r0 + i;
        #pragma unroll
        for (int j = 0; j < NSPAN; ++j) {
            bool in = (s >= s0[j]) && (s <= s1[j]);
            float vx = in ? v.x : -INFINITY;
            float vy = in ? v.y : -INFINITY;
            float vz = in ? v.z : -INFINITY;
            float vw = in ? v.w : -INFINITY;
            m[j].x = fmaxf(m[j].x, vx); m[j].y = fmaxf(m[j].y, vy);
            m[j].z = fmaxf(m[j].z, vz); m[j].w = fmaxf(m[j].w, vw);
        }
    }

    #pragma unroll
    for (int j = 0; j < NSPAN; ++j) {
        if (s1[j] >= r0 && s0[j] < r0 + RPC) {
            *(float4*)(partial + (((size_t)(b*nch + c))*NSPAN + j) * D + t*4) = m[j];
        }
    }
}

// ---------------------------------------------------------------------------
// Pool phase 2: one block per (b, span j); reduce intersecting chunks.
// ---------------------------------------------------------------------------
__global__ void k_pool2(const float* __restrict__ partial,
                        const int* __restrict__ h_span,
                        const int* __restrict__ t_span,
                        const int* __restrict__ b_spans,
                        float* __restrict__ pooled, int rpc) {
    int task = blockIdx.x;
    int b = task / NSPAN, j = task % NSPAN;
    int s0, s1, row;
    if (j == 0)      { s0 = h_span[b*2]; s1 = h_span[b*2+1]; row = b; }
    else if (j == 1) { s0 = t_span[b*2]; s1 = t_span[b*2+1]; row = B + b; }
    else {
        int k = j - 2;
        s0 = b_spans[(b*K+k)*2]; s1 = b_spans[(b*K+k)*2 + 1];
        row = 2*B + b*K + k;
    }
    int nch = S / rpc;
    int c0 = s0 / rpc, c1 = s1 / rpc;
    int t = threadIdx.x;
    float4 m = make_float4(-INFINITY, -INFINITY, -INFINITY, -INFINITY);
    for (int c = c0; c <= c1; ++c) {
        float4 v = *(const float4*)(partial + (((size_t)(b*nch + c))*NSPAN + j) * D + t*4);
        m.x = fmaxf(m.x, v.x); m.y = fmaxf(m.y, v.y);
        m.z = fmaxf(m.z, v.z); m.w = fmaxf(m.w, v.w);
    }
    ((float4*)(pooled + (size_t)row * D))[t] = m;
}

// ---------------------------------------------------------------------------
// Projection GEMM: p_part[ks][m][e] over K-slice. grid (12, 10, KS), 256 thr.
// ---------------------------------------------------------------------------
template<int KSPLIT>
__global__ void k_gemm(const float* __restrict__ pooled,
                       const float* __restrict__ wu,
                       const float* __restrict__ wv,
                       const float* __restrict__ wi,
                       float* __restrict__ p_part) {
    __shared__ float At[16][68];
    __shared__ float Wt[16][68];
    int e0 = blockIdx.x * 64;
    int m0 = blockIdx.y * 64;
    const int klen = D / KSPLIT;
    int dbase = blockIdx.z * klen;
    const float* Wm = (m0 < B) ? wu : (m0 < 2*B) ? wv : wi;

    int tid = threadIdx.x;
    int tx = tid & 15, ty = tid >> 4;
    int lm = tid >> 2;
    int ld = (tid & 3) * 4;

    float acc[4][4] = {};
    const int kchunks = klen / 16;
    #pragma unroll 2
    for (int kc = 0; kc < kchunks; ++kc) {
        int d0 = dbase + kc * 16;
        float4 a4 = *(const float4*)(pooled + (size_t)(m0 + lm) * D + d0 + ld);
        float4 w4 = *(const float4*)(Wm     + (size_t)(e0 + lm) * D + d0 + ld);
        __syncthreads();
        At[ld+0][lm] = a4.x; At[ld+1][lm] = a4.y; At[ld+2][lm] = a4.z; At[ld+3][lm] = a4.w;
        Wt[ld+0][lm] = w4.x; Wt[ld+1][lm] = w4.y; Wt[ld+2][lm] = w4.z; Wt[ld+3][lm] = w4.w;
        __syncthreads();
        #pragma unroll
        for (int dd = 0; dd < 16; ++dd) {
            float4 av  = *(const float4*)&At[dd][ty << 2];
            float4 wvv = *(const float4*)&Wt[dd][tx << 2];
            float a_[4] = {av.x, av.y, av.z, av.w};
            float w_[4] = {wvv.x, wvv.y, wvv.z, wvv.w};
            #pragma unroll
            for (int i = 0; i < 4; ++i)
                #pragma unroll
                for (int jj = 0; jj < 4; ++jj)
                    acc[i][jj] += a_[i] * w_[jj];
        }
    }
    #pragma unroll
    for (int i = 0; i < 4; ++i) {
        float4 o = make_float4(acc[i][0], acc[i][1], acc[i][2], acc[i][3]);
        *(float4*)(p_part + ((size_t)blockIdx.z * M_TOT + m0 + ty*4 + i) * D + e0 + tx*4) = o;
    }
}

// ---------------------------------------------------------------------------
// Attention: reduce partials+bias -> U,V,BI; dots; softmax; s = U+V+ctx.
// One block per b, 512 threads (8 waves = 8 dots in parallel).
// ---------------------------------------------------------------------------
template<int KSPLIT>
__global__ __launch_bounds__(512)
void k_att2(const float* __restrict__ p_part,
            const float* __restrict__ wu_b,
            const float* __restrict__ wv_b,
            const float* __restrict__ wi_b,
            float* __restrict__ s_out) {
    __shared__ float U[D], V[D], BI[K][D];
    __shared__ float dots[K];
    int b = blockIdx.x, tid = threadIdx.x;

    for (int task = tid; task < NSPAN * (D/4); task += 512) {
        int j = task / (D/4), sl = task % (D/4);
        size_t row = (j == 0) ? (size_t)b : (j == 1) ? (size_t)(B + b)
                   : (size_t)(2*B + b*K + (j - 2));
        const float* bias = (j == 0) ? wu_b : (j == 1) ? wv_b : wi_b;
        float4 acc = *(const float4*)(bias + sl*4);
        #pragma unroll
        for (int ks = 0; ks < KSPLIT; ++ks) {
            float4 p = *(const float4*)(p_part + ((size_t)ks * M_TOT + row) * D + sl*4);
            acc.x += p.x; acc.y += p.y; acc.z += p.z; acc.w += p.w;
        }
        float* dst = (j == 0) ? U : (j == 1) ? V : BI[j-2];
        *(float4*)(dst + sl*4) = acc;
    }
    __syncthreads();

    int wave = tid >> 6, lane = tid & 63;
    {
        float part = 0.f;
        #pragma unroll
        for (int i = 0; i < D/64; ++i) {
            int d = i*64 + lane;
            part += U[d] * BI[wave][d];
        }
        #pragma unroll
        for (int off = 32; off > 0; off >>= 1) part += __shfl_xor(part, off);
        if (lane == 0) dots[wave] = part * 0.125f;   // 1/sqrt(D_K=64)
    }
    __syncthreads();

    float mx = -INFINITY;
    #pragma unroll
    for (int k = 0; k < K; ++k) mx = fmaxf(mx, dots[k]);
    float ex[K], sum = 0.f;
    #pragma unroll
    for (int k = 0; k < K; ++k) { ex[k] = expf(dots[k] - mx); sum += ex[k]; }
    float inv = 1.f / sum;
    for (int d = tid; d < D; d += 512) {
        float c = 0.f;
        #pragma unroll
        for (int k = 0; k < K; ++k) c += ex[k] * BI[k][d];
        s_out[(size_t)b * D + d] = U[d] + V[d] + c * inv;
    }
}

// ---------------------------------------------------------------------------
// pair GEMM partials: pair_part[ks][m][e] = sum_{d in slice} s[m][d]*ln1_w[e][d]
// grid (12, KS), 256 thr. M=64 (all batches in one tile).
// ---------------------------------------------------------------------------
template<int KS>
__global__ void k_pairg(const float* __restrict__ s,
                        const float* __restrict__ ln1_w,
                        float* __restrict__ pair_part) {
    __shared__ float At[16][68];
    __shared__ float Wt[16][68];
    int e0 = blockIdx.x * 64;
    int dbase = blockIdx.y * (D / KS);

    int tid = threadIdx.x;
    int tx = tid & 15, ty = tid >> 4;
    int lm = tid >> 2;
    int ld = (tid & 3) * 4;

    float acc[4][4] = {};
    #pragma unroll 2
    for (int kc = 0; kc < (D/KS)/16; ++kc) {
        int d0 = dbase + kc * 16;
        float4 a4 = *(const float4*)(s     + (size_t)lm * D + d0 + ld);
        float4 w4 = *(const float4*)(ln1_w + (size_t)(e0 + lm) * D + d0 + ld);
        __syncthreads();
        At[ld+0][lm] = a4.x; At[ld+1][lm] = a4.y; At[ld+2][lm] = a4.z; At[ld+3][lm] = a4.w;
        Wt[ld+0][lm] = w4.x; Wt[ld+1][lm] = w4.y; Wt[ld+2][lm] = w4.z; Wt[ld+3][lm] = w4.w;
        __syncthreads();
        #pragma unroll
        for (int dd = 0; dd < 16; ++dd) {
            float4 av  = *(const float4*)&At[dd][ty << 2];
            float4 wvv = *(const float4*)&Wt[dd][tx << 2];
            float a_[4] = {av.x, av.y, av.z, av.w};
            float w_[4] = {wvv.x, wvv.y, wvv.z, wvv.w};
            #pragma unroll
            for (int i = 0; i < 4; ++i)
                #pragma unroll
                for (int jj = 0; jj < 4; ++jj)
                    acc[i][jj] += a_[i] * w_[jj];
        }
    }
    #pragma unroll
    for (int i = 0; i < 4; ++i) {
        float4 o = make_float4(acc[i][0], acc[i][1], acc[i][2], acc[i][3]);
        *(float4*)(pair_part + ((size_t)blockIdx.y * B + ty*4 + i) * D + e0 + tx*4) = o;
    }
}

// ---------------------------------------------------------------------------
// pred GEMM partials: A-tile (pair) built on the fly = relu(sum pair_part+bias).
// pred_part[ksp][m][r]. grid (RPAD/64=5, KSP), 256 thr. W rows clamped at R.
// ---------------------------------------------------------------------------
template<int KSP, int KSPAIR>
__global__ void k_predg(const float* __restrict__ pair_part,
                        const float* __restrict__ ln1_b,
                        const float* __restrict__ pred_w,
                        float* __restrict__ pred_part) {
    __shared__ float At[16][68];
    __shared__ float Wt[16][68];
    int r0 = blockIdx.x * 64;
    int dbase = blockIdx.y * (D / KSP);

    int tid = threadIdx.x;
    int tx = tid & 15, ty = tid >> 4;
    int lm = tid >> 2;
    int ld = (tid & 3) * 4;

    float acc[4][4] = {};
    #pragma unroll 2
    for (int kc = 0; kc < (D/KSP)/16; ++kc) {
        int d0 = dbase + kc * 16;
        // A element: pair[lm][d0+ld..+3] = relu(sum_ks pair_part + ln1_b)
        float4 a4 = *(const float4*)(ln1_b + d0 + ld);
        #pragma unroll
        for (int ks = 0; ks < KSPAIR; ++ks) {
            float4 p = *(const float4*)(pair_part + ((size_t)ks * B + lm) * D + d0 + ld);
            a4.x += p.x; a4.y += p.y; a4.z += p.z; a4.w += p.w;
        }
        a4.x = fmaxf(a4.x, 0.f); a4.y = fmaxf(a4.y, 0.f);
        a4.z = fmaxf(a4.z, 0.f); a4.w = fmaxf(a4.w, 0.f);
        int r = r0 + lm; if (r >= R) r = R - 1;     // clamp (unused rows)
        float4 w4 = *(const float4*)(pred_w + (size_t)r * D + d0 + ld);
        __syncthreads();
        At[ld+0][lm] = a4.x; At[ld+1][lm] = a4.y; At[ld+2][lm] = a4.z; At[ld+3][lm] = a4.w;
        Wt[ld+0][lm] = w4.x; Wt[ld+1][lm] = w4.y; Wt[ld+2][lm] = w4.z; Wt[ld+3][lm] = w4.w;
        __syncthreads();
        #pragma unroll
        for (int dd = 0; dd < 16; ++dd) {
            float4 av  = *(const float4*)&At[dd][ty << 2];
            float4 wvv = *(const float4*)&Wt[dd][tx << 2];
            float a_[4] = {av.x, av.y, av.z, av.w};
            float w_[4] = {wvv.x, wvv.y, wvv.z, wvv.w};
            #pragma unroll
            for (int i = 0; i < 4; ++i)
                #pragma unroll
                for (int jj = 0; jj < 4; ++jj)
                    acc[i][jj] += a_[i] * w_[jj];
        }
    }
    #pragma unroll
    for (int i = 0; i < 4; ++i) {
        float4 o = make_float4(acc[i][0], acc[i][1], acc[i][2], acc[i][3]);
        *(float4*)(pred_part + ((size_t)blockIdx.y * B + ty*4 + i) * RPAD + r0 + tx*4) = o;
    }
}

// ---------------------------------------------------------------------------
// Final: out[b][r] = sum_ksp pred_part[ksp][b][r] + pred_b[r]. 80 blocks.
// ---------------------------------------------------------------------------
template<int KSP>
__global__ void k_fin(const float* __restrict__ pred_part,
                      const float* __restrict__ pred_b,
                      float* __restrict__ out) {
    int idx = blockIdx.x * 256 + threadIdx.x;   // 0 .. B*RPAD
    int b = idx / RPAD, r = idx % RPAD;
    if (b < B && r < R) {
        float a = pred_b[r];
        #pragma unroll
        for (int ks = 0; ks < KSP; ++ks)
            a += pred_part[((size_t)ks * B + b) * RPAD + r];
        out[(size_t)b * R + r] = a;
    }
}

// ---------------------------------------------------------------------------
extern "C" void kernel_launch(void* const* d_in, const int* in_sizes, int n_in,
                              void* d_out, int out_size, void* d_ws, size_t ws_size,
                              hipStream_t stream) {
    const float* emb     = (const float*)d_in[0];
    const int*   h_span  = (const int*)  d_in[1];
    const int*   t_span  = (const int*)  d_in[2];
    const int*   b_spans = (const int*)  d_in[3];
    const float* wu_w    = (const float*)d_in[4];
    const float* wu_b    = (const float*)d_in[5];
    const float* wv_w    = (const float*)d_in[6];
    const float* wv_b    = (const float*)d_in[7];
    const float* wi_w    = (const float*)d_in[8];
    const float* wi_b    = (const float*)d_in[9];
    const float* ln1_w   = (const float*)d_in[10];
    const float* ln1_b   = (const float*)d_in[11];
    const float* pred_w  = (const float*)d_in[12];
    const float* pred_b  = (const float*)d_in[13];
    float* out = (float*)d_out;

    const int KSPLIT = 4;   // projection GEMM k-split
    const int KSP    = 4;   // pair/pred GEMM k-split
    size_t avail = ws_size / sizeof(float);
    auto need = [&](int nch_) -> size_t {
        return (size_t)M_TOT*D + (size_t)KSPLIT*M_TOT*D + (size_t)B*D
             + (size_t)KSP*B*D + (size_t)KSP*B*RPAD + (size_t)B*nch_*NSPAN*D;
    };
    int nch = (need(32) <= avail) ? 32 : 16;

    float* ws        = (float*)d_ws;
    float* pooled    = ws;                                     // M_TOT*D
    float* p_part    = pooled    + (size_t)M_TOT * D;          // KSPLIT*M_TOT*D
    float* s_buf     = p_part    + (size_t)KSPLIT * M_TOT * D; // B*D
    float* pair_part = s_buf     + (size_t)B * D;              // KSP*B*D
    float* pred_part = pair_part + (size_t)KSP * B * D;        // KSP*B*RPAD
    float* partial   = pred_part + (size_t)KSP * B * RPAD;     // B*nch*NSPAN*D

    if (nch == 32)
        k_pool1<16><<<dim3(B, 32), 192, 0, stream>>>(emb, h_span, t_span, b_spans, partial);
    else
        k_pool1<32><<<dim3(B, 16), 192, 0, stream>>>(emb, h_span, t_span, b_spans, partial);
    k_pool2<<<M_TOT, 192, 0, stream>>>(partial, h_span, t_span, b_spans, pooled, S / nch);
    k_gemm<KSPLIT><<<dim3(D/64, M_TOT/64, KSPLIT), 256, 0, stream>>>(pooled, wu_w, wv_w, wi_w, p_part);
    k_att2<KSPLIT><<<B, 512, 0, stream>>>(p_part, wu_b, wv_b, wi_b, s_buf);
    k_pairg<KSP><<<dim3(D/64, KSP), 256, 0, stream>>>(s_buf, ln1_w, pair_part);
    k_predg<KSP, KSP><<<dim3(RPAD/64, KSP), 256, 0, stream>>>(pair_part, ln1_b, pred_w, pred_part);
    k_fin<KSP><<<(B*RPAD + 255)/256, 256, 0, stream>>>(pred_part, pred_b, out);
}

// Round 7
// 71.944 us; speedup vs baseline: 1.9995x; 1.1421x over previous
//
#include <hip/hip_runtime.h>
#include <hip/hip_bf16.h>

// Problem constants
#define B 64
#define S 512
#define D 768
#define K 8
#define R 277
#define RPAD 320     // R padded to 5*64 for the pred GEMM
#define NSPAN 10     // h, t, 8 bridge spans per batch
#define M_TOT 640    // pooled rows: [u: 0..63][v: 64..127][bi: 128..639]

// ---------------------------------------------------------------------------
// Pool phase 1 (streaming, branchless): one block per (b, s-chunk).
// ---------------------------------------------------------------------------
template<int RPC>
__global__ void k_pool1(const float* __restrict__ emb,
                        const int* __restrict__ h_span,
                        const int* __restrict__ t_span,
                        const int* __restrict__ b_spans,
                        float* __restrict__ partial) {
    int b = blockIdx.x, c = blockIdx.y;
    int nch = S / RPC;
    int r0 = c * RPC;
    int t = threadIdx.x;

    int s0[NSPAN], s1[NSPAN];
    s0[0] = h_span[b*2]; s1[0] = h_span[b*2+1];
    s0[1] = t_span[b*2]; s1[1] = t_span[b*2+1];
    #pragma unroll
    for (int k = 0; k < K; ++k) {
        s0[2+k] = b_spans[(b*K+k)*2];
        s1[2+k] = b_spans[(b*K+k)*2 + 1];
    }

    bool any = false;
    #pragma unroll
    for (int j = 0; j < NSPAN; ++j)
        any |= (s1[j] >= r0) && (s0[j] < r0 + RPC);
    if (!any) return;

    float4 m[NSPAN];
    #pragma unroll
    for (int j = 0; j < NSPAN; ++j)
        m[j] = make_float4(-INFINITY, -INFINITY, -INFINITY, -INFINITY);

    const float4* e4 = (const float4*)(emb + (size_t)b * S * D) + (size_t)r0 * (D/4) + t;
    #pragma unroll
    for (int i = 0; i < RPC; ++i) {
        float4 v = e4[i * (D/4)];
        int s = r0 + i;
        #pragma unroll
        for (int j = 0; j < NSPAN; ++j) {
            bool in = (s >= s0[j]) && (s <= s1[j]);
            float vx = in ? v.x : -INFINITY;
            float vy = in ? v.y : -INFINITY;
            float vz = in ? v.z : -INFINITY;
            float vw = in ? v.w : -INFINITY;
            m[j].x = fmaxf(m[j].x, vx); m[j].y = fmaxf(m[j].y, vy);
            m[j].z = fmaxf(m[j].z, vz); m[j].w = fmaxf(m[j].w, vw);
        }
    }

    #pragma unroll
    for (int j = 0; j < NSPAN; ++j) {
        if (s1[j] >= r0 && s0[j] < r0 + RPC) {
            *(float4*)(partial + (((size_t)(b*nch + c))*NSPAN + j) * D + t*4) = m[j];
        }
    }
}

// ---------------------------------------------------------------------------
// Pool phase 2: one block per (b, span j); reduce intersecting chunks.
// ---------------------------------------------------------------------------
__global__ void k_pool2(const float* __restrict__ partial,
                        const int* __restrict__ h_span,
                        const int* __restrict__ t_span,
                        const int* __restrict__ b_spans,
                        float* __restrict__ pooled, int rpc) {
    int task = blockIdx.x;
    int b = task / NSPAN, j = task % NSPAN;
    int s0, s1, row;
    if (j == 0)      { s0 = h_span[b*2]; s1 = h_span[b*2+1]; row = b; }
    else if (j == 1) { s0 = t_span[b*2]; s1 = t_span[b*2+1]; row = B + b; }
    else {
        int k = j - 2;
        s0 = b_spans[(b*K+k)*2]; s1 = b_spans[(b*K+k)*2 + 1];
        row = 2*B + b*K + k;
    }
    int nch = S / rpc;
    int c0 = s0 / rpc, c1 = s1 / rpc;
    int t = threadIdx.x;
    float4 m = make_float4(-INFINITY, -INFINITY, -INFINITY, -INFINITY);
    for (int c = c0; c <= c1; ++c) {
        float4 v = *(const float4*)(partial + (((size_t)(b*nch + c))*NSPAN + j) * D + t*4);
        m.x = fmaxf(m.x, v.x); m.y = fmaxf(m.y, v.y);
        m.z = fmaxf(m.z, v.z); m.w = fmaxf(m.w, v.w);
    }
    ((float4*)(pooled + (size_t)row * D))[t] = m;
}

// ---------------------------------------------------------------------------
// Shared 16-step LDS-tile FMA block (64x64 tile, 4x4 regs/thread).
// ---------------------------------------------------------------------------
__device__ __forceinline__
void tile_fma(const float (*At)[68], const float (*Wt)[68],
              int tx, int ty, float acc[4][4]) {
    #pragma unroll
    for (int dd = 0; dd < 16; ++dd) {
        float4 av  = *(const float4*)&At[dd][ty << 2];
        float4 wvv = *(const float4*)&Wt[dd][tx << 2];
        float a_[4] = {av.x, av.y, av.z, av.w};
        float w_[4] = {wvv.x, wvv.y, wvv.z, wvv.w};
        #pragma unroll
        for (int i = 0; i < 4; ++i)
            #pragma unroll
            for (int jj = 0; jj < 4; ++jj)
                acc[i][jj] += a_[i] * w_[jj];
    }
}

// ---------------------------------------------------------------------------
// Projection GEMM, software-pipelined staging (prefetch kc+1 during compute).
// grid (12, 10, KSPLIT), 256 thr.
// ---------------------------------------------------------------------------
template<int KSPLIT>
__global__ void k_gemm(const float* __restrict__ pooled,
                       const float* __restrict__ wu,
                       const float* __restrict__ wv,
                       const float* __restrict__ wi,
                       float* __restrict__ p_part) {
    __shared__ float At[16][68];
    __shared__ float Wt[16][68];
    int e0 = blockIdx.x * 64;
    int m0 = blockIdx.y * 64;
    const int klen = D / KSPLIT;
    int dbase = blockIdx.z * klen;
    const float* Wm = (m0 < B) ? wu : (m0 < 2*B) ? wv : wi;

    int tid = threadIdx.x;
    int tx = tid & 15, ty = tid >> 4;
    int lm = tid >> 2;
    int ld = (tid & 3) * 4;

    const float* arow = pooled + (size_t)(m0 + lm) * D + ld + dbase;
    const float* wrow = Wm     + (size_t)(e0 + lm) * D + ld + dbase;

    float acc[4][4] = {};
    const int NK = klen / 16;
    float4 a4 = *(const float4*)(arow);
    float4 w4 = *(const float4*)(wrow);
    for (int kc = 0; kc < NK; ++kc) {
        __syncthreads();
        At[ld+0][lm] = a4.x; At[ld+1][lm] = a4.y; At[ld+2][lm] = a4.z; At[ld+3][lm] = a4.w;
        Wt[ld+0][lm] = w4.x; Wt[ld+1][lm] = w4.y; Wt[ld+2][lm] = w4.z; Wt[ld+3][lm] = w4.w;
        __syncthreads();
        if (kc + 1 < NK) {                         // prefetch next chunk
            a4 = *(const float4*)(arow + (kc+1)*16);
            w4 = *(const float4*)(wrow + (kc+1)*16);
        }
        tile_fma(At, Wt, tx, ty, acc);
    }
    #pragma unroll
    for (int i = 0; i < 4; ++i) {
        float4 o = make_float4(acc[i][0], acc[i][1], acc[i][2], acc[i][3]);
        *(float4*)(p_part + ((size_t)blockIdx.z * M_TOT + m0 + ty*4 + i) * D + e0 + tx*4) = o;
    }
}

// ---------------------------------------------------------------------------
// Attention: reduce partials+bias -> U,V,BI; dots; softmax; s = U+V+ctx.
// ---------------------------------------------------------------------------
template<int KSPLIT>
__global__ __launch_bounds__(512)
void k_att2(const float* __restrict__ p_part,
            const float* __restrict__ wu_b,
            const float* __restrict__ wv_b,
            const float* __restrict__ wi_b,
            float* __restrict__ s_out) {
    __shared__ float U[D], V[D], BI[K][D];
    __shared__ float dots[K];
    int b = blockIdx.x, tid = threadIdx.x;

    for (int task = tid; task < NSPAN * (D/4); task += 512) {
        int j = task / (D/4), sl = task % (D/4);
        size_t row = (j == 0) ? (size_t)b : (j == 1) ? (size_t)(B + b)
                   : (size_t)(2*B + b*K + (j - 2));
        const float* bias = (j == 0) ? wu_b : (j == 1) ? wv_b : wi_b;
        float4 acc = *(const float4*)(bias + sl*4);
        #pragma unroll
        for (int ks = 0; ks < KSPLIT; ++ks) {
            float4 p = *(const float4*)(p_part + ((size_t)ks * M_TOT + row) * D + sl*4);
            acc.x += p.x; acc.y += p.y; acc.z += p.z; acc.w += p.w;
        }
        float* dst = (j == 0) ? U : (j == 1) ? V : BI[j-2];
        *(float4*)(dst + sl*4) = acc;
    }
    __syncthreads();

    int wave = tid >> 6, lane = tid & 63;
    {
        float part = 0.f;
        #pragma unroll
        for (int i = 0; i < D/64; ++i) {
            int d = i*64 + lane;
            part += U[d] * BI[wave][d];
        }
        #pragma unroll
        for (int off = 32; off > 0; off >>= 1) part += __shfl_xor(part, off);
        if (lane == 0) dots[wave] = part * 0.125f;   // 1/sqrt(D_K=64)
    }
    __syncthreads();

    float mx = -INFINITY;
    #pragma unroll
    for (int k = 0; k < K; ++k) mx = fmaxf(mx, dots[k]);
    float ex[K], sum = 0.f;
    #pragma unroll
    for (int k = 0; k < K; ++k) { ex[k] = expf(dots[k] - mx); sum += ex[k]; }
    float inv = 1.f / sum;
    for (int d = tid; d < D; d += 512) {
        float c = 0.f;
        #pragma unroll
        for (int k = 0; k < K; ++k) c += ex[k] * BI[k][d];
        s_out[(size_t)b * D + d] = U[d] + V[d] + c * inv;
    }
}

// ---------------------------------------------------------------------------
// pair GEMM partials, pipelined: grid (12, KS=8), 256 thr.
// ---------------------------------------------------------------------------
template<int KS>
__global__ void k_pairg(const float* __restrict__ s,
                        const float* __restrict__ ln1_w,
                        float* __restrict__ pair_part) {
    __shared__ float At[16][68];
    __shared__ float Wt[16][68];
    int e0 = blockIdx.x * 64;
    int dbase = blockIdx.y * (D / KS);

    int tid = threadIdx.x;
    int tx = tid & 15, ty = tid >> 4;
    int lm = tid >> 2;
    int ld = (tid & 3) * 4;

    const float* arow = s     + (size_t)lm * D + ld + dbase;
    const float* wrow = ln1_w + (size_t)(e0 + lm) * D + ld + dbase;

    float acc[4][4] = {};
    const int NK = (D/KS) / 16;
    float4 a4 = *(const float4*)(arow);
    float4 w4 = *(const float4*)(wrow);
    for (int kc = 0; kc < NK; ++kc) {
        __syncthreads();
        At[ld+0][lm] = a4.x; At[ld+1][lm] = a4.y; At[ld+2][lm] = a4.z; At[ld+3][lm] = a4.w;
        Wt[ld+0][lm] = w4.x; Wt[ld+1][lm] = w4.y; Wt[ld+2][lm] = w4.z; Wt[ld+3][lm] = w4.w;
        __syncthreads();
        if (kc + 1 < NK) {
            a4 = *(const float4*)(arow + (kc+1)*16);
            w4 = *(const float4*)(wrow + (kc+1)*16);
        }
        tile_fma(At, Wt, tx, ty, acc);
    }
    #pragma unroll
    for (int i = 0; i < 4; ++i) {
        float4 o = make_float4(acc[i][0], acc[i][1], acc[i][2], acc[i][3]);
        *(float4*)(pair_part + ((size_t)blockIdx.y * B + ty*4 + i) * D + e0 + tx*4) = o;
    }
}

// ---------------------------------------------------------------------------
// pair finalize: pair = relu(sum_ks pair_part + ln1_b). 48 blocks x 256.
// ---------------------------------------------------------------------------
template<int KS>
__global__ void k_pairfin(const float* __restrict__ pair_part,
                          const float* __restrict__ ln1_b,
                          float* __restrict__ pair) {
    int task = blockIdx.x * 256 + threadIdx.x;   // 0 .. B*D/4
    int m = task / (D/4), sl = task % (D/4);
    float4 a = *(const float4*)(ln1_b + sl*4);
    #pragma unroll
    for (int ks = 0; ks < KS; ++ks) {
        float4 p = *(const float4*)(pair_part + ((size_t)ks * B + m) * D + sl*4);
        a.x += p.x; a.y += p.y; a.z += p.z; a.w += p.w;
    }
    a.x = fmaxf(a.x, 0.f); a.y = fmaxf(a.y, 0.f);
    a.z = fmaxf(a.z, 0.f); a.w = fmaxf(a.w, 0.f);
    *(float4*)(pair + (size_t)m * D + sl*4) = a;
}

// ---------------------------------------------------------------------------
// pred GEMM partials, pipelined: reads pair directly. grid (5, KSP=8), 256 thr.
// ---------------------------------------------------------------------------
template<int KSP>
__global__ void k_predg(const float* __restrict__ pair,
                        const float* __restrict__ pred_w,
                        float* __restrict__ pred_part) {
    __shared__ float At[16][68];
    __shared__ float Wt[16][68];
    int r0 = blockIdx.x * 64;
    int dbase = blockIdx.y * (D / KSP);

    int tid = threadIdx.x;
    int tx = tid & 15, ty = tid >> 4;
    int lm = tid >> 2;
    int ld = (tid & 3) * 4;

    int r = r0 + lm; if (r >= R) r = R - 1;      // clamp (unused rows)
    const float* arow = pair   + (size_t)lm * D + ld + dbase;
    const float* wrow = pred_w + (size_t)r * D + ld + dbase;

    float acc[4][4] = {};
    const int NK = (D/KSP) / 16;
    float4 a4 = *(const float4*)(arow);
    float4 w4 = *(const float4*)(wrow);
    for (int kc = 0; kc < NK; ++kc) {
        __syncthreads();
        At[ld+0][lm] = a4.x; At[ld+1][lm] = a4.y; At[ld+2][lm] = a4.z; At[ld+3][lm] = a4.w;
        Wt[ld+0][lm] = w4.x; Wt[ld+1][lm] = w4.y; Wt[ld+2][lm] = w4.z; Wt[ld+3][lm] = w4.w;
        __syncthreads();
        if (kc + 1 < NK) {
            a4 = *(const float4*)(arow + (kc+1)*16);
            w4 = *(const float4*)(wrow + (kc+1)*16);
        }
        tile_fma(At, Wt, tx, ty, acc);
    }
    #pragma unroll
    for (int i = 0; i < 4; ++i) {
        float4 o = make_float4(acc[i][0], acc[i][1], acc[i][2], acc[i][3]);
        *(float4*)(pred_part + ((size_t)blockIdx.y * B + ty*4 + i) * RPAD + r0 + tx*4) = o;
    }
}

// ---------------------------------------------------------------------------
// Final: out[b][r] = sum_ksp pred_part[ksp][b][r] + pred_b[r]. 80 blocks.
// ---------------------------------------------------------------------------
template<int KSP>
__global__ void k_fin(const float* __restrict__ pred_part,
                      const float* __restrict__ pred_b,
                      float* __restrict__ out) {
    int idx = blockIdx.x * 256 + threadIdx.x;   // 0 .. B*RPAD
    int b = idx / RPAD, r = idx % RPAD;
    if (b < B && r < R) {
        float a = pred_b[r];
        #pragma unroll
        for (int ks = 0; ks < KSP; ++ks)
            a += pred_part[((size_t)ks * B + b) * RPAD + r];
        out[(size_t)b * R + r] = a;
    }
}

// ---------------------------------------------------------------------------
extern "C" void kernel_launch(void* const* d_in, const int* in_sizes, int n_in,
                              void* d_out, int out_size, void* d_ws, size_t ws_size,
                              hipStream_t stream) {
    const float* emb     = (const float*)d_in[0];
    const int*   h_span  = (const int*)  d_in[1];
    const int*   t_span  = (const int*)  d_in[2];
    const int*   b_spans = (const int*)  d_in[3];
    const float* wu_w    = (const float*)d_in[4];
    const float* wu_b    = (const float*)d_in[5];
    const float* wv_w    = (const float*)d_in[6];
    const float* wv_b    = (const float*)d_in[7];
    const float* wi_w    = (const float*)d_in[8];
    const float* wi_b    = (const float*)d_in[9];
    const float* ln1_w   = (const float*)d_in[10];
    const float* ln1_b   = (const float*)d_in[11];
    const float* pred_w  = (const float*)d_in[12];
    const float* pred_b  = (const float*)d_in[13];
    float* out = (float*)d_out;

    const int KSPLIT = 4;   // projection GEMM k-split
    const int KS     = 8;   // pair/pred GEMM k-split
    size_t avail = ws_size / sizeof(float);
    auto need = [&](int nch_) -> size_t {
        return (size_t)M_TOT*D + (size_t)KSPLIT*M_TOT*D + (size_t)B*D
             + (size_t)KS*B*D + (size_t)B*D + (size_t)KS*B*RPAD
             + (size_t)B*nch_*NSPAN*D;
    };
    int nch = (need(32) <= avail) ? 32 : 16;

    float* ws        = (float*)d_ws;
    float* pooled    = ws;                                     // M_TOT*D
    float* p_part    = pooled    + (size_t)M_TOT * D;          // KSPLIT*M_TOT*D
    float* s_buf     = p_part    + (size_t)KSPLIT * M_TOT * D; // B*D
    float* pair_part = s_buf     + (size_t)B * D;              // KS*B*D
    float* pair      = pair_part + (size_t)KS * B * D;         // B*D
    float* pred_part = pair      + (size_t)B * D;              // KS*B*RPAD
    float* partial   = pred_part + (size_t)KS * B * RPAD;      // B*nch*NSPAN*D

    if (nch == 32)
        k_pool1<16><<<dim3(B, 32), 192, 0, stream>>>(emb, h_span, t_span, b_spans, partial);
    else
        k_pool1<32><<<dim3(B, 16), 192, 0, stream>>>(emb, h_span, t_span, b_spans, partial);
    k_pool2<<<M_TOT, 192, 0, stream>>>(partial, h_span, t_span, b_spans, pooled, S / nch);
    k_gemm<KSPLIT><<<dim3(D/64, M_TOT/64, KSPLIT), 256, 0, stream>>>(pooled, wu_w, wv_w, wi_w, p_part);
    k_att2<KSPLIT><<<B, 512, 0, stream>>>(p_part, wu_b, wv_b, wi_b, s_buf);
    k_pairg<KS><<<dim3(D/64, KS), 256, 0, stream>>>(s_buf, ln1_w, pair_part);
    k_pairfin<KS><<<(B*(D/4) + 255)/256, 256, 0, stream>>>(pair_part, ln1_b, pair);
    k_predg<KS><<<dim3(RPAD/64, KS), 256, 0, stream>>>(pair, pred_w, pred_part);
    k_fin<KS><<<(B*RPAD + 255)/256, 256, 0, stream>>>(pred_part, pred_b, out);
}